// Round 8
// baseline (48.613 us; speedup 1.0000x reference)
//
#include <hip/hip_runtime.h>
#include <math.h>

// Problem constants (match reference setup_inputs)
#define BS 32
#define NA 3
#define NC 80
#define HH 52
#define WW 52
#define TPER 50                 // targets per batch image
#define NTT (BS * TPER)         // 1600 total targets
#define HW (HH * WW)            // 2704
#define CPB (NA * HW)           // 8112 cells per batch image
#define CH (5 + NC)             // 85 channels per anchor
#define CELLS_PER_BLK 1024      // 256 threads x 4 cells each
#define CBPB 8                  // cell-blocks per batch: 8*1024 >= 8112
#define NCELLBLK (BS * CBPB)    // 256 cells-role blocks
#define NBLK (NCELLBLK + NTT)   // 1856 blocks total (even)

__device__ __forceinline__ float sigm(float v) { return 1.0f / (1.0f + expf(-v)); }

__device__ __forceinline__ float wave_red(float t) {
    #pragma unroll
    for (int off = 32; off > 0; off >>= 1) t += __shfl_down(t, off);  // width 64
    return t;
}

// ws layout: float2 ws[NBLK] = {pre-weighted loss partial, valid-target flag}
// followed by unsigned counter (zeroed by a memset node each call).

__global__ __launch_bounds__(256) void k_main(const float* __restrict__ in,
                                              const float* __restrict__ tgt,
                                              float2* __restrict__ ws,
                                              unsigned* __restrict__ cnt,
                                              float* __restrict__ out)
{
    __shared__ float4 sbox[TPER];                 // {x1, x2, y1, y2}
    __shared__ int scell[TPER], scls[TPER];
    __shared__ unsigned sbm[CELLS_PER_BLK / 32];  // target-cell bitmap (cells role)
    __shared__ float wred[4];
    __shared__ int slast;
    const int tid = threadIdx.x;
    const float aw[3] = {1.25f, 2.0f, 4.125f};
    const float ah[3] = {1.625f, 3.75f, 2.875f};

    float term = 0.0f;
    float flag = 0.0f;

    if (blockIdx.x < NCELLBLK) {
        // ---------------- cells role: noobj BCE + a_loss, 4 cells/thread ----------------
        const int b  = blockIdx.x >> 3;           // / CBPB
        const int lo = (blockIdx.x & 7) * CELLS_PER_BLK;
        if (tid < CELLS_PER_BLK / 32) sbm[tid] = 0u;
        int mycell = -1;
        if (tid < TPER) {
            const float* p = tgt + (size_t)(b * TPER + tid) * 5;
            float c0 = p[0], c1 = p[1], c2 = p[2], c3 = p[3], c4 = p[4];
            bool valid = (c0 + c1 + c2 + c3 + c4) > 0.0f;
            float gx = c1 * WW, gy = c2 * HH, gw = c3 * WW, gh = c4 * HH;
            int gi = (int)gx; gi = gi < 0 ? 0 : (gi > WW - 1 ? WW - 1 : gi);
            int gj = (int)gy; gj = gj < 0 ? 0 : (gj > HH - 1 ? HH - 1 : gj);
            int bn = 0; float best = -1.0f;
            for (int a = 0; a < 3; ++a) {
                float inter = fminf(gw, aw[a]) * fminf(gh, ah[a]);
                float uni = gw * gh + aw[a] * ah[a] - inter;
                float iou = inter / (uni + 1e-16f);
                if (iou > best) { best = iou; bn = a; }   // strict >: argmax keeps first
            }
            if (valid) {
                sbox[tid] = make_float4(gx - 0.5f * gw, gx + 0.5f * gw,
                                        gy - 0.5f * gh, gy + 0.5f * gh);
                mycell = bn * HW + gj * WW + gi;
            } else {
                sbox[tid] = make_float4(1e30f, 1e30f, 1e30f, 1e30f);  // inert sentinel
            }
        }
        __syncthreads();
        if (mycell >= lo && mycell < lo + CELLS_PER_BLK)
            atomicOr(&sbm[(mycell - lo) >> 5], 1u << ((mycell - lo) & 31));
        __syncthreads();

        const int idx0 = lo + tid;
        float P1[4], P2[4], Q1[4], Q2[4], A2[4], CF[4];
        bool ACT[4], IGN[4] = {false, false, false, false};
        #pragma unroll
        for (int k = 0; k < 4; ++k) {
            int idx = idx0 + k * 256;
            ACT[k] = idx < CPB;
            P1[k] = 0.0f; P2[k] = 0.0f; Q1[k] = 0.0f; Q2[k] = 0.0f;
            A2[k] = 1e30f; CF[k] = 0.5f;
            if (ACT[k]) {
                int a = idx / HW;
                int r = idx - a * HW;
                int yy = r / WW;
                int xx = r - yy * WW;
                const float* base = in + ((size_t)b * (NA * CH) + a * CH) * HW + r;
                float xr = base[0], yr = base[HW], wr = base[2 * HW],
                      hr = base[3 * HW], cr = base[4 * HW];
                float sx = sigm(xr), sy = sigm(yr);
                CF[k] = sigm(cr);
                float px = sx + (float)xx, py = sy + (float)yy;
                float pw = expf(wr) * aw[a], ph = expf(hr) * ah[a];
                P1[k] = px - 0.5f * pw; P2[k] = px + 0.5f * pw;
                Q1[k] = py - 0.5f * ph; Q2[k] = py + 0.5f * ph;
                A2[k] = pw * ph + 1e-16f;
                term += 0.05f * ((sx - 0.5f) * (sx - 0.5f) + (sy - 0.5f) * (sy - 0.5f)
                                 + wr * wr + hr * hr);        // 0.1/2 pre-weight
            }
        }
        for (int t = 0; t < TPER; ++t) {
            float4 bx = sbox[t];                              // one ds_read_b128 / target
            float ar = (bx.y - bx.x) * (bx.w - bx.z);         // area1 (0 for sentinel)
            #pragma unroll
            for (int k = 0; k < 4; ++k) {
                float iw = fmaxf(fminf(bx.y, P2[k]) - fmaxf(bx.x, P1[k]), 0.0f);
                float ih = fmaxf(fminf(bx.w, Q2[k]) - fmaxf(bx.z, Q1[k]), 0.0f);
                float inter = iw * ih;
                // iou >= 0.5  <=>  3*inter >= area1 + area2 + eps (denominator > 0)
                IGN[k] = IGN[k] || (3.0f * inter >= ar + A2[k]);
            }
        }
        #pragma unroll
        for (int k = 0; k < 4; ++k) {
            int d = tid + k * 256;
            bool ist = (sbm[d >> 5] >> (d & 31)) & 1u;
            if (ACT[k] && !IGN[k] && !ist)
                term += -logf(fmaxf(1.0f - CF[k], 1e-12f));   // noobj pre-weight 5*0.2=1
        }
    } else {
        // ---------------- obj role: one target per block ----------------
        const int i = blockIdx.x - NCELLBLK;       // global target index
        const int b = i / TPER;
        const int t = i - b * TPER;
        if (tid < TPER) {
            const float* p = tgt + (size_t)(b * TPER + tid) * 5;
            float c0 = p[0], c1 = p[1], c2 = p[2], c3 = p[3], c4 = p[4];
            bool valid = (c0 + c1 + c2 + c3 + c4) > 0.0f;
            float gx = c1 * WW, gy = c2 * HH, gw = c3 * WW, gh = c4 * HH;
            int gi = (int)gx; gi = gi < 0 ? 0 : (gi > WW - 1 ? WW - 1 : gi);
            int gj = (int)gy; gj = gj < 0 ? 0 : (gj > HH - 1 ? HH - 1 : gj);
            int bn = 0; float best = -1.0f;
            for (int a = 0; a < 3; ++a) {
                float inter = fminf(gw, aw[a]) * fminf(gh, ah[a]);
                float uni = gw * gh + aw[a] * ah[a] - inter;
                float iou = inter / (uni + 1e-16f);
                if (iou > best) { best = iou; bn = a; }
            }
            scell[tid] = valid ? (bn * HW + gj * WW + gi) : -1;
            int cls = (int)c0; cls = cls < 0 ? 0 : (cls > NC - 1 ? NC - 1 : cls);
            scls[tid] = cls;
        }
        __syncthreads();
        const int cell = scell[t];                 // broadcast via LDS
        int a = 0, r = 0;
        float v = 0.0f;
        if (cell >= 0) {                           // issue scattered loads EARLY
            a = cell / HW;
            r = cell - a * HW;
            const float* bp = in + ((size_t)b * (NA * CH) + a * CH) * HW + r;
            if (tid < 85) v = bp[(size_t)tid * HW];   // channel == tid
        }
        const int lane = tid & 63;                 // same pattern in every wave
        bool m = (lane < TPER) && (cell >= 0) && (scell[lane] == cell);
        unsigned long long mask = __ballot(m);     // matching valid targets
        bool owner = (cell >= 0) && ((mask >> (t + 1)) == 0ULL);  // no later writer
        flag = (cell >= 0) ? 1.0f : 0.0f;
        if (owner) {                               // mask logic overlapped load latency
            if (tid < 5) {
                const float* p = tgt + (size_t)i * 5;
                if (tid == 0) {
                    float gx = p[1] * WW; int gi = r - (r / WW) * WW;
                    float d = sigm(v) - (gx - (float)gi); term = 0.5f * d * d;
                } else if (tid == 1) {
                    float gy = p[2] * HH; int gj = r / WW;
                    float d = sigm(v) - (gy - (float)gj); term = 0.5f * d * d;
                } else if (tid == 2) {
                    float d = v - logf(p[3] * WW / aw[a] + 1e-16f); term = 0.5f * d * d;
                } else if (tid == 3) {
                    float d = v - logf(p[4] * HH / ah[a] + 1e-16f); term = 0.5f * d * d;
                } else {
                    term = -5.0f * logf(fmaxf(sigm(v), 1e-12f));
                }
            } else if (tid < 85) {
                int c = tid - 5;
                bool pos = false;                  // multi-hot union over colliding targets
                unsigned long long mm = mask;
                while (mm) { int t2 = __ffsll(mm) - 1; mm &= mm - 1; pos = pos || (scls[t2] == c); }
                float p = sigm(v);
                term = pos ? -logf(fmaxf(p, 1e-12f)) : -logf(fmaxf(1.0f - p, 1e-12f));
            }
        }
    }

    // ---- common tail: block reduce, publish partial, last block reduces all ----
    {
        float tr = wave_red(term);
        if ((tid & 63) == 0) wred[tid >> 6] = tr;
        __syncthreads();
        if (tid == 0) {
            ws[blockIdx.x] = make_float2(wred[0] + wred[1] + wred[2] + wred[3], flag);
            __threadfence();                                   // publish before signal
            unsigned old = atomicAdd(cnt, 1u);
            slast = (old == (unsigned)(NBLK - 1)) ? 1 : 0;
        }
        __syncthreads();
        if (slast) {
            __threadfence();                                   // acquire all partials
            const float4* w4 = (const float4*)ws;              // NBLK/2 = 928 float4
            float s = 0.0f, nv = 0.0f;
            for (int i = tid; i < NBLK / 2; i += 256) {
                float4 x = w4[i];
                s += x.x + x.z;
                nv += x.y + x.w;
            }
            s = wave_red(s);
            nv = wave_red(nv);
            __syncthreads();                                   // wred reuse safe
            if ((tid & 63) == 0) wred[tid >> 6] = s;
            __syncthreads();
            float S = wred[0] + wred[1] + wred[2] + wred[3];
            __syncthreads();
            if ((tid & 63) == 0) wred[tid >> 6] = nv;
            __syncthreads();
            if (tid == 0) {
                float N = wred[0] + wred[1] + wred[2] + wred[3];
                out[0] = S / fmaxf(N, 1.0f);
            }
        }
    }
}

extern "C" void kernel_launch(void* const* d_in, const int* in_sizes, int n_in,
                              void* d_out, int out_size, void* d_ws, size_t ws_size,
                              hipStream_t stream)
{
    const float* in = (const float*)d_in[0];
    const float* tgt = (const float*)d_in[1];
    float2* ws = (float2*)d_ws;
    unsigned* cnt = (unsigned*)((char*)d_ws + (size_t)NBLK * sizeof(float2));

    // zero the completion counter each call (poison-proof, graph-capturable)
    hipMemsetAsync((void*)cnt, 0, sizeof(unsigned), stream);
    k_main<<<NBLK, 256, 0, stream>>>(in, tgt, ws, cnt, (float*)d_out);
}

// Round 9
// 18.529 us; speedup vs baseline: 2.6236x; 2.6236x over previous
//
#include <hip/hip_runtime.h>
#include <math.h>

// Problem constants (match reference setup_inputs)
#define BS 32
#define NA 3
#define NC 80
#define HH 52
#define WW 52
#define TPER 50                 // targets per batch image
#define NTT (BS * TPER)         // 1600 total targets
#define HW (HH * WW)            // 2704
#define CPB (NA * HW)           // 8112 cells per batch image
#define CH (5 + NC)             // 85 channels per anchor
#define CELLS_PER_BLK 1024      // 256 threads x 4 cells each
#define CBPB 8                  // cell-blocks per batch: 8*1024 >= 8112
#define NCELLBLK (BS * CBPB)    // 256 cells-role blocks
#define OBJ_PAIRS 25            // 2 targets per obj block
#define NOBJBLK (BS * OBJ_PAIRS)// 800 obj blocks
#define NBLK (NCELLBLK + NOBJBLK) // 1056 blocks (even)

// fast transcendentals: v_exp_f32 (2^x), v_log_f32 (log2 x), v_rcp_f32
__device__ __forceinline__ float fexp(float x) { return __builtin_amdgcn_exp2f(x * 1.4426950408889634f); }
__device__ __forceinline__ float flog(float x) { return __builtin_amdgcn_logf(x) * 0.6931471805599453f; }
__device__ __forceinline__ float sigm(float v) { return __builtin_amdgcn_rcpf(1.0f + fexp(-v)); }

__device__ __forceinline__ float wave_red(float t) {
    #pragma unroll
    for (int off = 32; off > 0; off >>= 1) t += __shfl_down(t, off);  // width 64
    return t;
}

// ws layout: float2 ws[NBLK] = {pre-weighted loss partial, n_valid contribution}

__global__ __launch_bounds__(256) void k_main(const float* __restrict__ in,
                                              const float* __restrict__ tgt,
                                              float2* __restrict__ ws)
{
    __shared__ float4 sbox[TPER];                 // {x1, x2, y1, y2} (cells role)
    __shared__ int scell[TPER], scls[TPER];
    __shared__ unsigned sbm[CELLS_PER_BLK / 32];  // target-cell bitmap (cells role)
    __shared__ float wred[4];
    const int tid = threadIdx.x;
    const float aw[3] = {1.25f, 2.0f, 4.125f};
    const float ah[3] = {1.625f, 3.75f, 2.875f};
    const float raw[3] = {0.8f, 0.5f, 0.24242424242424243f};       // 1/aw
    const float rah[3] = {0.6153846153846154f, 0.26666666666666666f, 0.34782608695652173f}; // 1/ah

    float term = 0.0f;
    float flag = 0.0f;

    if (blockIdx.x < NCELLBLK) {
        // ---------------- cells role: noobj BCE + a_loss, 4 cells/thread ----------------
        const int b  = blockIdx.x >> 3;           // / CBPB
        const int lo = (blockIdx.x & 7) * CELLS_PER_BLK;
        if (tid < CELLS_PER_BLK / 32) sbm[tid] = 0u;
        int mycell = -1;
        if (tid < TPER) {
            const float* p = tgt + (size_t)(b * TPER + tid) * 5;
            float c0 = p[0], c1 = p[1], c2 = p[2], c3 = p[3], c4 = p[4];
            bool valid = (c0 + c1 + c2 + c3 + c4) > 0.0f;
            float gx = c1 * WW, gy = c2 * HH, gw = c3 * WW, gh = c4 * HH;
            int gi = (int)gx; gi = gi < 0 ? 0 : (gi > WW - 1 ? WW - 1 : gi);
            int gj = (int)gy; gj = gj < 0 ? 0 : (gj > HH - 1 ? HH - 1 : gj);
            // anchor argmax via cross-multiplication (no divides); strict > keeps first
            int bn = 0;
            {
                float bi = fminf(gw, aw[0]) * fminf(gh, ah[0]);
                float bu = gw * gh + aw[0] * ah[0] - bi;
                #pragma unroll
                for (int a = 1; a < 3; ++a) {
                    float ia = fminf(gw, aw[a]) * fminf(gh, ah[a]);
                    float ua = gw * gh + aw[a] * ah[a] - ia;
                    if (ia * bu > bi * ua) { bn = a; bi = ia; bu = ua; }
                }
            }
            if (valid) {
                sbox[tid] = make_float4(gx - 0.5f * gw, gx + 0.5f * gw,
                                        gy - 0.5f * gh, gy + 0.5f * gh);
                mycell = bn * HW + gj * WW + gi;
            } else {
                sbox[tid] = make_float4(1e30f, 1e30f, 1e30f, 1e30f);  // inert sentinel
            }
        }
        __syncthreads();
        if (mycell >= lo && mycell < lo + CELLS_PER_BLK)
            atomicOr(&sbm[(mycell - lo) >> 5], 1u << ((mycell - lo) & 31));
        __syncthreads();

        const int idx0 = lo + tid;
        float P1[4], P2[4], Q1[4], Q2[4], A2[4], CF[4];
        bool ACT[4], IGN[4] = {false, false, false, false};
        #pragma unroll
        for (int k = 0; k < 4; ++k) {
            int idx = idx0 + k * 256;
            ACT[k] = idx < CPB;
            P1[k] = 0.0f; P2[k] = 0.0f; Q1[k] = 0.0f; Q2[k] = 0.0f;
            A2[k] = 1e30f; CF[k] = 0.5f;
            if (ACT[k]) {
                int a = idx / HW;
                int r = idx - a * HW;
                int yy = r / WW;
                int xx = r - yy * WW;
                const float* base = in + ((size_t)b * (NA * CH) + a * CH) * HW + r;
                float xr = base[0], yr = base[HW], wr = base[2 * HW],
                      hr = base[3 * HW], cr = base[4 * HW];
                float sx = sigm(xr), sy = sigm(yr);
                CF[k] = sigm(cr);
                float px = sx + (float)xx, py = sy + (float)yy;
                float pw = fexp(wr) * aw[a], ph = fexp(hr) * ah[a];
                P1[k] = px - 0.5f * pw; P2[k] = px + 0.5f * pw;
                Q1[k] = py - 0.5f * ph; Q2[k] = py + 0.5f * ph;
                A2[k] = pw * ph + 1e-16f;
                term += 0.05f * ((sx - 0.5f) * (sx - 0.5f) + (sy - 0.5f) * (sy - 0.5f)
                                 + wr * wr + hr * hr);        // 0.1/2 pre-weight
            }
        }
        #pragma unroll 2
        for (int t = 0; t < TPER; ++t) {
            float4 bx = sbox[t];                              // one ds_read_b128 / target
            float ar = (bx.y - bx.x) * (bx.w - bx.z);         // area1 (0 for sentinel)
            #pragma unroll
            for (int k = 0; k < 4; ++k) {
                float iw = fmaxf(fminf(bx.y, P2[k]) - fmaxf(bx.x, P1[k]), 0.0f);
                float ih = fmaxf(fminf(bx.w, Q2[k]) - fmaxf(bx.z, Q1[k]), 0.0f);
                float inter = iw * ih;
                // iou >= 0.5  <=>  3*inter >= area1 + area2 + eps (denominator > 0)
                IGN[k] = IGN[k] || (3.0f * inter >= ar + A2[k]);
            }
        }
        #pragma unroll
        for (int k = 0; k < 4; ++k) {
            int d = tid + k * 256;
            bool ist = (sbm[d >> 5] >> (d & 31)) & 1u;
            if (ACT[k] && !IGN[k] && !ist)
                term += -flog(fmaxf(1.0f - CF[k], 1e-12f));   // noobj pre-weight 5*0.2=1
        }
    } else {
        // ---------------- obj role: TWO targets per block ----------------
        const int o = blockIdx.x - NCELLBLK;       // 0..NOBJBLK-1
        const int b = o / OBJ_PAIRS;
        const int pair = o - b * OBJ_PAIRS;
        const int tA = 2 * pair;                   // this block's two targets
        if (tid < TPER) {
            const float* p = tgt + (size_t)(b * TPER + tid) * 5;
            float c0 = p[0], c1 = p[1], c2 = p[2], c3 = p[3], c4 = p[4];
            bool valid = (c0 + c1 + c2 + c3 + c4) > 0.0f;
            float gx = c1 * WW, gy = c2 * HH, gw = c3 * WW, gh = c4 * HH;
            int gi = (int)gx; gi = gi < 0 ? 0 : (gi > WW - 1 ? WW - 1 : gi);
            int gj = (int)gy; gj = gj < 0 ? 0 : (gj > HH - 1 ? HH - 1 : gj);
            int bn = 0;
            {
                float bi = fminf(gw, aw[0]) * fminf(gh, ah[0]);
                float bu = gw * gh + aw[0] * ah[0] - bi;
                #pragma unroll
                for (int a = 1; a < 3; ++a) {
                    float ia = fminf(gw, aw[a]) * fminf(gh, ah[a]);
                    float ua = gw * gh + aw[a] * ah[a] - ia;
                    if (ia * bu > bi * ua) { bn = a; bi = ia; bu = ua; }
                }
            }
            scell[tid] = valid ? (bn * HW + gj * WW + gi) : -1;
            int cls = (int)c0; cls = cls < 0 ? 0 : (cls > NC - 1 ? NC - 1 : cls);
            scls[tid] = cls;
        }
        __syncthreads();
        const int half = tid >> 7;                 // 0: target tA, 1: target tA+1
        const int myT = tA + half;
        const int k = tid & 127;                   // channel index within half
        const int cell = scell[myT];               // LDS broadcast
        int a = 0, r = 0;
        float v = 0.0f;
        if (cell >= 0 && k < 85) {                 // issue scattered loads EARLY
            a = cell / HW;
            r = cell - a * HW;
            v = in[((size_t)b * (NA * CH) + a * CH + k) * HW + r];
        }
        // per-wave ballot: every wave's lanes test scell[lane] vs ITS half's cell
        const int lane = tid & 63;
        bool m = (lane < TPER) && (cell >= 0) && (scell[lane] == cell);
        unsigned long long mask = __ballot(m);     // valid targets mapping to same cell
        bool owner = (cell >= 0) && ((mask >> (myT + 1)) == 0ULL);  // no later writer
        if (owner) {                               // mask logic overlapped load latency
            if (k < 5) {
                const float* p = tgt + (size_t)(b * TPER + myT) * 5;
                if (k == 0) {
                    float gx = p[1] * WW; int gi = r - (r / WW) * WW;
                    float d = sigm(v) - (gx - (float)gi); term = 0.5f * d * d;
                } else if (k == 1) {
                    float gy = p[2] * HH; int gj = r / WW;
                    float d = sigm(v) - (gy - (float)gj); term = 0.5f * d * d;
                } else if (k == 2) {
                    float d = v - flog(p[3] * WW * raw[a] + 1e-16f); term = 0.5f * d * d;
                } else if (k == 3) {
                    float d = v - flog(p[4] * HH * rah[a] + 1e-16f); term = 0.5f * d * d;
                } else {
                    term = -5.0f * flog(fmaxf(sigm(v), 1e-12f));
                }
            } else if (k < 85) {
                int c = k - 5;
                bool pos = false;                  // multi-hot union over colliding targets
                unsigned long long mm = mask;
                while (mm) { int t2 = __ffsll(mm) - 1; mm &= mm - 1; pos = pos || (scls[t2] == c); }
                float p = sigm(v);
                term = pos ? -flog(fmaxf(p, 1e-12f)) : -flog(fmaxf(1.0f - p, 1e-12f));
            }
        }
        if (tid == 0)
            flag = (scell[tA] >= 0 ? 1.0f : 0.0f) + (scell[tA + 1] >= 0 ? 1.0f : 0.0f);
    }

    // ---- common tail: block reduce, one float2 store ----
    float tr = wave_red(term);
    if ((tid & 63) == 0) wred[tid >> 6] = tr;
    __syncthreads();
    if (tid == 0)
        ws[blockIdx.x] = make_float2(wred[0] + wred[1] + wred[2] + wred[3], flag);
}

// Final reduce: 528 float4 loads; loss = sum(partials) / max(n_valid, 1)
__global__ __launch_bounds__(256) void k_final(const float2* __restrict__ ws,
                                               float* __restrict__ out)
{
    const int tid = threadIdx.x;
    const float4* w4 = (const float4*)ws;          // NBLK/2 = 528 float4
    float s = 0.0f, nv = 0.0f;
    for (int i = tid; i < NBLK / 2; i += 256) {
        float4 v = w4[i];
        s += v.x + v.z;
        nv += v.y + v.w;
    }
    __shared__ float wr0[4], wr1[4];
    s = wave_red(s);
    nv = wave_red(nv);
    if ((tid & 63) == 0) { wr0[tid >> 6] = s; wr1[tid >> 6] = nv; }
    __syncthreads();
    if (tid == 0) {
        float S = wr0[0] + wr0[1] + wr0[2] + wr0[3];
        float N = wr1[0] + wr1[1] + wr1[2] + wr1[3];
        out[0] = S / fmaxf(N, 1.0f);
    }
}

extern "C" void kernel_launch(void* const* d_in, const int* in_sizes, int n_in,
                              void* d_out, int out_size, void* d_ws, size_t ws_size,
                              hipStream_t stream)
{
    const float* in = (const float*)d_in[0];
    const float* tgt = (const float*)d_in[1];
    float2* ws = (float2*)d_ws;

    k_main<<<NBLK, 256, 0, stream>>>(in, tgt, ws);
    k_final<<<1, 256, 0, stream>>>(ws, (float*)d_out);
}

// Round 10
// 17.501 us; speedup vs baseline: 2.7778x; 1.0588x over previous
//
#include <hip/hip_runtime.h>
#include <math.h>

// Problem constants (match reference setup_inputs)
#define BS 32
#define NA 3
#define NC 80
#define HH 52
#define WW 52
#define TPER 50                 // targets per batch image
#define NTT (BS * TPER)         // 1600 total targets
#define HW (HH * WW)            // 2704
#define CPB (NA * HW)           // 8112 cells per batch image (divisible by 4)
#define CH (5 + NC)             // 85 channels per anchor
#define CELLS_PER_BLK 1024      // 256 threads x 4 CONSECUTIVE cells each
#define CBPB 8                  // cell-blocks per batch: 8*1024 >= 8112
#define NCELLBLK (BS * CBPB)    // 256 cells-role blocks
#define OBJ_PAIRS 25            // 2 targets per obj block
#define NOBJBLK (BS * OBJ_PAIRS)// 800 obj blocks
#define NBLK (NCELLBLK + NOBJBLK) // 1056 blocks (even)

// fast transcendentals: v_exp_f32 (2^x), v_log_f32 (log2 x), v_rcp_f32
__device__ __forceinline__ float fexp(float x) { return __builtin_amdgcn_exp2f(x * 1.4426950408889634f); }
__device__ __forceinline__ float flog(float x) { return __builtin_amdgcn_logf(x) * 0.6931471805599453f; }
__device__ __forceinline__ float sigm(float v) { return __builtin_amdgcn_rcpf(1.0f + fexp(-v)); }

__device__ __forceinline__ float wave_red(float t) {
    #pragma unroll
    for (int off = 32; off > 0; off >>= 1) t += __shfl_down(t, off);  // width 64
    return t;
}

// ws layout: float2 ws[NBLK] = {pre-weighted loss partial, n_valid contribution}

__global__ __launch_bounds__(256) void k_main(const float* __restrict__ in,
                                              const float* __restrict__ tgt,
                                              float2* __restrict__ ws)
{
    __shared__ float4 sbox[TPER];                 // {x1, x2, y1, y2} (cells role)
    __shared__ unsigned sbm[CELLS_PER_BLK / 32];  // target-cell bitmap (cells role)
    __shared__ float wred[4];
    const int tid = threadIdx.x;
    const float aw[3] = {1.25f, 2.0f, 4.125f};
    const float ah[3] = {1.625f, 3.75f, 2.875f};
    const float raw[3] = {0.8f, 0.5f, 0.24242424242424243f};       // 1/aw
    const float rah[3] = {0.6153846153846154f, 0.26666666666666666f, 0.34782608695652173f}; // 1/ah

    float term = 0.0f;
    float flag = 0.0f;

    if (blockIdx.x < NCELLBLK) {
        // ------- cells role: noobj BCE + a_loss, 4 CONSECUTIVE cells/thread -------
        const int b  = blockIdx.x >> 3;           // / CBPB
        const int lo = (blockIdx.x & 7) * CELLS_PER_BLK;
        if (tid < CELLS_PER_BLK / 32) sbm[tid] = 0u;
        int mycell = -1;
        if (tid < TPER) {
            const float* p = tgt + (size_t)(b * TPER + tid) * 5;
            float c0 = p[0], c1 = p[1], c2 = p[2], c3 = p[3], c4 = p[4];
            bool valid = (c0 + c1 + c2 + c3 + c4) > 0.0f;
            float gx = c1 * WW, gy = c2 * HH, gw = c3 * WW, gh = c4 * HH;
            int gi = (int)gx; gi = gi < 0 ? 0 : (gi > WW - 1 ? WW - 1 : gi);
            int gj = (int)gy; gj = gj < 0 ? 0 : (gj > HH - 1 ? HH - 1 : gj);
            // anchor argmax via cross-multiplication; strict > keeps first on tie
            int bn = 0;
            {
                float bi = fminf(gw, aw[0]) * fminf(gh, ah[0]);
                float bu = gw * gh + aw[0] * ah[0] - bi;
                #pragma unroll
                for (int a = 1; a < 3; ++a) {
                    float ia = fminf(gw, aw[a]) * fminf(gh, ah[a]);
                    float ua = gw * gh + aw[a] * ah[a] - ia;
                    if (ia * bu > bi * ua) { bn = a; bi = ia; bu = ua; }
                }
            }
            if (valid) {
                sbox[tid] = make_float4(gx - 0.5f * gw, gx + 0.5f * gw,
                                        gy - 0.5f * gh, gy + 0.5f * gh);
                mycell = bn * HW + gj * WW + gi;
            } else {
                sbox[tid] = make_float4(1e30f, 1e30f, 1e30f, 1e30f);  // inert sentinel
            }
        }
        __syncthreads();
        if (mycell >= lo && mycell < lo + CELLS_PER_BLK)
            atomicOr(&sbm[(mycell - lo) >> 5], 1u << ((mycell - lo) & 31));
        __syncthreads();

        const int q0 = lo + 4 * tid;              // quad base; 4-aligned, CPB%4==0 ->
        const bool actq = q0 < CPB;               // whole quad valid or whole invalid
        float P1[4], P2[4], Q1[4], Q2[4], A2[4], CF[4];
        bool IGN[4] = {false, false, false, false};
        #pragma unroll
        for (int k = 0; k < 4; ++k) { P1[k]=0; P2[k]=0; Q1[k]=0; Q2[k]=0; A2[k]=1e30f; CF[k]=0.5f; }
        if (actq) {
            // HW%4==0, WW%4==0: quad never crosses anchor plane or grid row
            const int a  = q0 / HW;
            const int r  = q0 - a * HW;
            const int yy = r / WW;
            const int xx0 = r - yy * WW;
            const float* plane = in + ((size_t)b * (NA * CH) + a * CH) * HW + r;
            float4 X = *(const float4*)(plane);
            float4 Y = *(const float4*)(plane + HW);
            float4 Wv = *(const float4*)(plane + 2 * HW);
            float4 Hv = *(const float4*)(plane + 3 * HW);
            float4 Cv = *(const float4*)(plane + 4 * HW);
            float xs[4] = {X.x, X.y, X.z, X.w};
            float ys[4] = {Y.x, Y.y, Y.z, Y.w};
            float zs[4] = {Wv.x, Wv.y, Wv.z, Wv.w};
            float hs[4] = {Hv.x, Hv.y, Hv.z, Hv.w};
            float cs[4] = {Cv.x, Cv.y, Cv.z, Cv.w};
            #pragma unroll
            for (int k = 0; k < 4; ++k) {
                float sx = sigm(xs[k]), sy = sigm(ys[k]);
                CF[k] = sigm(cs[k]);
                float px = sx + (float)(xx0 + k), py = sy + (float)yy;
                float pw = fexp(zs[k]) * aw[a], ph = fexp(hs[k]) * ah[a];
                P1[k] = px - 0.5f * pw; P2[k] = px + 0.5f * pw;
                Q1[k] = py - 0.5f * ph; Q2[k] = py + 0.5f * ph;
                A2[k] = pw * ph + 1e-16f;
                term += 0.05f * ((sx - 0.5f) * (sx - 0.5f) + (sy - 0.5f) * (sy - 0.5f)
                                 + zs[k] * zs[k] + hs[k] * hs[k]);   // 0.1/2 pre-weight
            }
        }
        #pragma unroll 2
        for (int t = 0; t < TPER; ++t) {
            float4 bx = sbox[t];                              // one broadcast b128 / target
            float ar = (bx.y - bx.x) * (bx.w - bx.z);         // area1 (0 for sentinel)
            #pragma unroll
            for (int k = 0; k < 4; ++k) {
                float iw = fmaxf(fminf(bx.y, P2[k]) - fmaxf(bx.x, P1[k]), 0.0f);
                float ih = fmaxf(fminf(bx.w, Q2[k]) - fmaxf(bx.z, Q1[k]), 0.0f);
                float inter = iw * ih;
                // iou >= 0.5  <=>  3*inter >= area1 + area2 + eps (denominator > 0)
                IGN[k] = IGN[k] || (3.0f * inter >= ar + A2[k]);
            }
        }
        if (actq) {
            #pragma unroll
            for (int k = 0; k < 4; ++k) {
                int d = 4 * tid + k;
                bool ist = (sbm[d >> 5] >> (d & 31)) & 1u;
                if (!IGN[k] && !ist)
                    term += -flog(fmaxf(1.0f - CF[k], 1e-12f));  // noobj pre-weight 5*0.2=1
            }
        }
    } else {
        // ------- obj role: TWO targets per block, barrier-free per-wave prep -------
        const int o = blockIdx.x - NCELLBLK;       // 0..NOBJBLK-1
        const int b = o / OBJ_PAIRS;
        const int pair = o - b * OBJ_PAIRS;
        const int tA = 2 * pair;                   // this block's two targets
        const int lane = tid & 63;
        const int wid = tid >> 6;                  // 0..3
        const int myT = tA + (wid >> 1);           // waves 0,1 -> tA; 2,3 -> tA+1
        const int k = ((wid & 1) << 6) | lane;     // channel index 0..127 (0..84 used)

        // every wave redundantly preps all 50 targets in registers (no LDS, no barrier)
        int celll = -1, clsl = 0;
        if (lane < TPER) {
            const float* p = tgt + (size_t)(b * TPER + lane) * 5;
            float c0 = p[0], c1 = p[1], c2 = p[2], c3 = p[3], c4 = p[4];
            bool valid = (c0 + c1 + c2 + c3 + c4) > 0.0f;
            float gx = c1 * WW, gy = c2 * HH, gw = c3 * WW, gh = c4 * HH;
            int gi = (int)gx; gi = gi < 0 ? 0 : (gi > WW - 1 ? WW - 1 : gi);
            int gj = (int)gy; gj = gj < 0 ? 0 : (gj > HH - 1 ? HH - 1 : gj);
            int bn = 0;
            {
                float bi = fminf(gw, aw[0]) * fminf(gh, ah[0]);
                float bu = gw * gh + aw[0] * ah[0] - bi;
                #pragma unroll
                for (int a = 1; a < 3; ++a) {
                    float ia = fminf(gw, aw[a]) * fminf(gh, ah[a]);
                    float ua = gw * gh + aw[a] * ah[a] - ia;
                    if (ia * bu > bi * ua) { bn = a; bi = ia; bu = ua; }
                }
            }
            celll = valid ? (bn * HW + gj * WW + gi) : -1;
            int cls = (int)c0; cls = cls < 0 ? 0 : (cls > NC - 1 ? NC - 1 : cls);
            clsl = cls;
        }
        const int cell = __shfl(celll, myT);       // my target's cell (wave-uniform)
        bool mt = (lane < TPER) && (cell >= 0) && (celll == cell);
        unsigned long long mask = __ballot(mt);    // valid targets mapping to same cell
        bool owner = (cell >= 0) && ((mask >> (myT + 1)) == 0ULL);  // no later writer
        int a = 0, r = 0;
        float v = 0.0f;
        if (cell >= 0 && k < 85) {                 // issue scattered load EARLY
            a = cell / HW;
            r = cell - a * HW;
            v = in[((size_t)b * (NA * CH) + a * CH + k) * HW + r];
        }
        if (owner && k < 85) {
            if (k < 5) {
                const float* p = tgt + (size_t)(b * TPER + myT) * 5;
                if (k == 0) {
                    float gx = p[1] * WW; int gi = r - (r / WW) * WW;
                    float d = sigm(v) - (gx - (float)gi); term = 0.5f * d * d;
                } else if (k == 1) {
                    float gy = p[2] * HH; int gj = r / WW;
                    float d = sigm(v) - (gy - (float)gj); term = 0.5f * d * d;
                } else if (k == 2) {
                    float d = v - flog(p[3] * WW * raw[a] + 1e-16f); term = 0.5f * d * d;
                } else if (k == 3) {
                    float d = v - flog(p[4] * HH * rah[a] + 1e-16f); term = 0.5f * d * d;
                } else {
                    term = -5.0f * flog(fmaxf(sigm(v), 1e-12f));
                }
            } else {
                int c = k - 5;
                bool pos = false;                  // multi-hot union over colliding targets
                unsigned long long mm = mask;
                while (mm) {
                    int t2 = __ffsll(mm) - 1; mm &= mm - 1;
                    pos = pos || (__shfl(clsl, t2) == c);   // bpermute reads src regs
                }
                float p = sigm(v);
                term = pos ? -flog(fmaxf(p, 1e-12f)) : -flog(fmaxf(1.0f - p, 1e-12f));
            }
        }
        // n_valid contribution for the pair (value consumed only at tid==0)
        int cA = __shfl(celll, tA), cB = __shfl(celll, tA + 1);
        flag = (cA >= 0 ? 1.0f : 0.0f) + (cB >= 0 ? 1.0f : 0.0f);
    }

    // ---- common tail: block reduce, one float2 store ----
    float tr = wave_red(term);
    if ((tid & 63) == 0) wred[tid >> 6] = tr;
    __syncthreads();
    if (tid == 0)
        ws[blockIdx.x] = make_float2(wred[0] + wred[1] + wred[2] + wred[3], flag);
}

// Final reduce: 528 float4 loads; loss = sum(partials) / max(n_valid, 1)
__global__ __launch_bounds__(256) void k_final(const float2* __restrict__ ws,
                                               float* __restrict__ out)
{
    const int tid = threadIdx.x;
    const float4* w4 = (const float4*)ws;          // NBLK/2 = 528 float4
    float s = 0.0f, nv = 0.0f;
    for (int i = tid; i < NBLK / 2; i += 256) {
        float4 v = w4[i];
        s += v.x + v.z;
        nv += v.y + v.w;
    }
    __shared__ float wr0[4], wr1[4];
    s = wave_red(s);
    nv = wave_red(nv);
    if ((tid & 63) == 0) { wr0[tid >> 6] = s; wr1[tid >> 6] = nv; }
    __syncthreads();
    if (tid == 0) {
        float S = wr0[0] + wr0[1] + wr0[2] + wr0[3];
        float N = wr1[0] + wr1[1] + wr1[2] + wr1[3];
        out[0] = S / fmaxf(N, 1.0f);
    }
}

extern "C" void kernel_launch(void* const* d_in, const int* in_sizes, int n_in,
                              void* d_out, int out_size, void* d_ws, size_t ws_size,
                              hipStream_t stream)
{
    const float* in = (const float*)d_in[0];
    const float* tgt = (const float*)d_in[1];
    float2* ws = (float2*)d_ws;

    k_main<<<NBLK, 256, 0, stream>>>(in, tgt, ws);
    k_final<<<1, 256, 0, stream>>>(ws, (float*)d_out);
}